// Round 14
// baseline (87.519 us; speedup 1.0000x reference)
//
#include <hip/hip_runtime.h>
#include <hip/hip_bf16.h>

// Problem constants (from reference setup_inputs)
#define BDIM 256     // batch
#define NDIM 1152    // route nodes
#define CIN 8
#define KDIM 10      // num capsule groups
#define COUT 16
#define NTHREADS 512
#define BT 2         // batches per block -> W[k] read once per 2 b's
#define NPT 9        // n values per thread = NDIM / 128
#define SLAB (NDIM * 4)          // uint4s per block slab in predG (4608)

// R14 = R13 split + the R9 spill discipline REAPPLIED to the new kernels.
// R13's regression was 100% allocator: no waves_per_eu pin -> kernel1 got
// 36 VGPR and spilled ~83 MB scratch (WRITE_SIZE 92 MB, VALUBusy 13%).
// amdgpu_waves_per_eu(8,8) pins a 64-VGPR cap; the fenced phase-1 live set
// is 52 (R9-proven), kernel2's is smaller -> zero spill at 8 waves/EU
// (4 blocks/CU -- double the monolith's LDS-capped occupancy, which is the
// entire point of splitting).
//   kernel 1: fenced phase-1, packs bf16 pred -> predG[blk][t+512j]
//             (coalesced dwordx4), psum reduce -> sT. LDS 1 KB.
//   kernel 2: reads sT, streams predG twice for the routing iters. LDS 4 KB.

#if defined(__has_builtin)
#  if __has_builtin(__builtin_amdgcn_exp2f)
#    define EXP2F(x) __builtin_amdgcn_exp2f(x)
#  endif
#  if __has_builtin(__builtin_amdgcn_rcpf)
#    define RCPF(x) __builtin_amdgcn_rcpf(x)
#  endif
#endif
#ifndef EXP2F
#  define EXP2F(x) exp2f(x)
#endif
#ifndef RCPF
#  define RCPF(x) (1.0f / (x))
#endif
#define LOG2E 1.4426950408889634f

__device__ __forceinline__ unsigned pack2(float a, float b) {   // v_cvt_pk_bf16_f32
    union { __hip_bfloat162 h; unsigned u; } cv;
    cv.h = __float22bfloat162_rn(make_float2(a, b));
    return cv.u;
}
__device__ __forceinline__ float bf_lo(unsigned u) { return __uint_as_float(u << 16); }
__device__ __forceinline__ float bf_hi(unsigned u) { return __uint_as_float(u & 0xffff0000u); }

// 8 FMAs: one W float4 (one i) against both batches' x scalar
#define FMA8(i, w4)                                                      \
    a0[0] = fmaf(xs0[i], (w4).x, a0[0]);                                 \
    a0[1] = fmaf(xs0[i], (w4).y, a0[1]);                                 \
    a0[2] = fmaf(xs0[i], (w4).z, a0[2]);                                 \
    a0[3] = fmaf(xs0[i], (w4).w, a0[3]);                                 \
    a1[0] = fmaf(xs1[i], (w4).x, a1[0]);                                 \
    a1[1] = fmaf(xs1[i], (w4).y, a1[1]);                                 \
    a1[2] = fmaf(xs1[i], (w4).z, a1[2]);                                 \
    a1[3] = fmaf(xs1[i], (w4).w, a1[3]);

// ---------------- Kernel 1: pred production + per-block co sums ----------
__global__ __attribute__((amdgpu_flat_work_group_size(NTHREADS, NTHREADS),
                          amdgpu_waves_per_eu(8, 8)))
void capsule_pred_kernel(const float* __restrict__ x,      // [B, N, CIN]
                         const float* __restrict__ w,      // [K, N, CIN, COUT]
                         uint4*       __restrict__ predG,  // [1280][4608]
                         float*       __restrict__ sTG)    // [1280][32]
{
    __shared__ float4 redP[8][4][2];       // [wv][coq][bb] psum, 1 KB

    const int blk = blockIdx.x;
    const int k   = blk >> 7;              // / (BDIM/BT) == 128
    const int b0  = (blk & 127) * BT;
    const int t   = threadIdx.x;
    const int wv  = t >> 6;
    const int l   = t & 63;
    const int coq = t & 3;                 // co = coq*4 .. coq*4+3
    const int nb  = t >> 2;                // base n (0..127)

    const float* __restrict__ xb0 = x + (size_t)b0 * NDIM * CIN;
    const float* __restrict__ xb1 = xb0 + NDIM * CIN;
    const float* __restrict__ wk  = w + (size_t)k * NDIM * CIN * COUT + coq * 4;
    uint4* __restrict__ slab = predG + (size_t)blk * SLAB;

    float ps0[4] = {0.f,0.f,0.f,0.f}, ps1[4] = {0.f,0.f,0.f,0.f};

#pragma unroll 1
    for (int j = 0; j < NPT; ++j) {
        const int n = nb + 128 * j;
        const float4 xa0 = *reinterpret_cast<const float4*>(xb0 + n * CIN);
        const float4 xc0 = *reinterpret_cast<const float4*>(xb0 + n * CIN + 4);
        const float4 xa1 = *reinterpret_cast<const float4*>(xb1 + n * CIN);
        const float4 xc1 = *reinterpret_cast<const float4*>(xb1 + n * CIN + 4);
        const float xs0[8] = {xa0.x,xa0.y,xa0.z,xa0.w,xc0.x,xc0.y,xc0.z,xc0.w};
        const float xs1[8] = {xa1.x,xa1.y,xa1.z,xa1.w,xc1.x,xc1.y,xc1.z,xc1.w};
        const float* wr = wk + (size_t)n * (CIN * COUT);
        float a0[4] = {0.f,0.f,0.f,0.f}, a1[4] = {0.f,0.f,0.f,0.f};
        {   // i = 0,1
            const float4 wA = *reinterpret_cast<const float4*>(wr);
            const float4 wB = *reinterpret_cast<const float4*>(wr + COUT);
            FMA8(0, wA); FMA8(1, wB);
        }
        __builtin_amdgcn_sched_barrier(0);  // bound W loads in flight to 2
        {   // i = 2,3
            const float4 wA = *reinterpret_cast<const float4*>(wr + 2 * COUT);
            const float4 wB = *reinterpret_cast<const float4*>(wr + 3 * COUT);
            FMA8(2, wA); FMA8(3, wB);
        }
        __builtin_amdgcn_sched_barrier(0);
        {   // i = 4,5
            const float4 wA = *reinterpret_cast<const float4*>(wr + 4 * COUT);
            const float4 wB = *reinterpret_cast<const float4*>(wr + 5 * COUT);
            FMA8(4, wA); FMA8(5, wB);
        }
        __builtin_amdgcn_sched_barrier(0);
        {   // i = 6,7
            const float4 wA = *reinterpret_cast<const float4*>(wr + 6 * COUT);
            const float4 wB = *reinterpret_cast<const float4*>(wr + 7 * COUT);
            FMA8(6, wA); FMA8(7, wB);
        }
        uint4 qq;
        qq.x = pack2(a0[0], a0[1]);
        qq.y = pack2(a0[2], a0[3]);
        qq.z = pack2(a1[0], a1[1]);
        qq.w = pack2(a1[2], a1[3]);
        slab[t + 512 * j] = qq;             // coalesced global_store_dwordx4
#pragma unroll
        for (int c = 0; c < 4; ++c) { ps0[c] += a0[c]; ps1[c] += a1[c]; }
        __builtin_amdgcn_sched_barrier(0);  // stop cross-j load hoisting
    }

    // intra-wave reduce over the 16 lanes sharing coq
#pragma unroll
    for (int m = 4; m < 64; m <<= 1) {
#pragma unroll
        for (int c = 0; c < 4; ++c) {
            ps0[c] += __shfl_xor(ps0[c], m, 64);
            ps1[c] += __shfl_xor(ps1[c], m, 64);
        }
    }
    if (l < 4) {
        redP[wv][l][0] = make_float4(ps0[0], ps0[1], ps0[2], ps0[3]);
        redP[wv][l][1] = make_float4(ps1[0], ps1[1], ps1[2], ps1[3]);
    }
    __syncthreads();
    if (t < 8) {                            // t = coq*2 + bb
        const int cq = t >> 1, bb = t & 1;
        float4 s = make_float4(0.f, 0.f, 0.f, 0.f);
#pragma unroll 1
        for (int wvi = 0; wvi < 8; ++wvi) {
            const float4 r = redP[wvi][cq][bb];
            s.x += r.x; s.y += r.y; s.z += r.z; s.w += r.w;
        }
        *reinterpret_cast<float4*>(sTG + blk * 32 + t * 4) = s;
    }
}

// ---------------- Kernel 2: routing iterations over predG ----------------
__global__ __attribute__((amdgpu_flat_work_group_size(NTHREADS, NTHREADS),
                          amdgpu_waves_per_eu(8, 8)))
void capsule_route_kernel(const uint4* __restrict__ predG,  // [1280][4608]
                          const float* __restrict__ sTG,    // [1280][32]
                          const int*   __restrict__ niter_p,
                          float*       __restrict__ out)    // [K, B, COUT]
{
    __shared__ float4 redI[2][8][4][4];    // [buf][wv][coq][{se0,sp0,se1,sp1}], 4 KB

    const int blk = blockIdx.x;
    const int k   = blk >> 7;
    const int b0  = (blk & 127) * BT;
    const int t   = threadIdx.x;
    const int wv  = t >> 6;
    const int l   = t & 63;
    const int coq = t & 3;
    const uint4* __restrict__ slab = predG + (size_t)blk * SLAB;

    // per-coq sums from kernel 1 (4-lane broadcast loads)
    const float4 s0 = *reinterpret_cast<const float4*>(sTG + blk * 32 + coq * 8);
    const float4 s1 = *reinterpret_cast<const float4*>(sTG + blk * 32 + coq * 8 + 4);
    const float sT0[4] = {s0.x, s0.y, s0.z, s0.w};
    const float sT1[4] = {s1.x, s1.y, s1.z, s1.w};

    const int niter = *niter_p;

    // Iteration 1: logits == 0 -> uniform softmax -> s = mean_n(pred)
    // v = s|s|/(1+s^2), s = sT/N == sT*|sT| / (N^2 + sT^2)
    float v0[4], v1[4], vc0[4], vc1[4];
    {
        const float N2 = (float)NDIM * (float)NDIM;
#pragma unroll
        for (int c = 0; c < 4; ++c) {
            v0[c] = sT0[c] * fabsf(sT0[c]) * RCPF(fmaf(sT0[c], sT0[c], N2));
            v1[c] = sT1[c] * fabsf(sT1[c]) * RCPF(fmaf(sT1[c], sT1[c], N2));
            vc0[c] = v0[c];
            vc1[c] = v1[c];
        }
    }

    for (int it = 1; it < niter; ++it) {
        const int itb = it & 1;
        float vl0[4], vl1[4];
#pragma unroll
        for (int c = 0; c < 4; ++c) { vl0[c] = vc0[c] * LOG2E; vl1[c] = vc1[c] * LOG2E; }

        float se0[4]={0.f,0.f,0.f,0.f}, sp0[4]={0.f,0.f,0.f,0.f};
        float se1[4]={0.f,0.f,0.f,0.f}, sp1[4]={0.f,0.f,0.f,0.f};
#pragma unroll 3
        for (int j = 0; j < NPT; ++j) {
            const uint4 q = slab[t + 512 * j];   // coalesced dwordx4, L2/L3-hot
            const float p0[4] = {bf_lo(q.x), bf_hi(q.x), bf_lo(q.y), bf_hi(q.y)};
            const float p1[4] = {bf_lo(q.z), bf_hi(q.z), bf_lo(q.w), bf_hi(q.w)};
#pragma unroll
            for (int c = 0; c < 4; ++c) {
                const float e0 = EXP2F(p0[c] * vl0[c]);   // no max-sub needed
                se0[c] += e0;
                sp0[c] = fmaf(e0, p0[c], sp0[c]);
                const float e1 = EXP2F(p1[c] * vl1[c]);
                se1[c] += e1;
                sp1[c] = fmaf(e1, p1[c], sp1[c]);
            }
        }
#pragma unroll
        for (int m = 4; m < 64; m <<= 1) {
#pragma unroll
            for (int c = 0; c < 4; ++c) {
                se0[c] += __shfl_xor(se0[c], m, 64);
                sp0[c] += __shfl_xor(sp0[c], m, 64);
                se1[c] += __shfl_xor(se1[c], m, 64);
                sp1[c] += __shfl_xor(sp1[c], m, 64);
            }
        }
        if (l < 4) {
            redI[itb][wv][l][0] = make_float4(se0[0], se0[1], se0[2], se0[3]);
            redI[itb][wv][l][1] = make_float4(sp0[0], sp0[1], sp0[2], sp0[3]);
            redI[itb][wv][l][2] = make_float4(se1[0], se1[1], se1[2], se1[3]);
            redI[itb][wv][l][3] = make_float4(sp1[0], sp1[1], sp1[2], sp1[3]);
        }
        __syncthreads();   // double-buffered redI: one barrier per iteration
        float seT0[4]={0.f,0.f,0.f,0.f}, spT0[4]={0.f,0.f,0.f,0.f};
        float seT1[4]={0.f,0.f,0.f,0.f}, spT1[4]={0.f,0.f,0.f,0.f};
#pragma unroll 1
        for (int wvi = 0; wvi < 8; ++wvi) {   // unroll 1: <=4 float4 live
            const float4 a = redI[itb][wvi][coq][0];
            const float4 b = redI[itb][wvi][coq][1];
            const float4 c4 = redI[itb][wvi][coq][2];
            const float4 d = redI[itb][wvi][coq][3];
            seT0[0]+=a.x; seT0[1]+=a.y; seT0[2]+=a.z; seT0[3]+=a.w;
            spT0[0]+=b.x; spT0[1]+=b.y; spT0[2]+=b.z; spT0[3]+=b.w;
            seT1[0]+=c4.x; seT1[1]+=c4.y; seT1[2]+=c4.z; seT1[3]+=c4.w;
            spT1[0]+=d.x; spT1[1]+=d.y; spT1[2]+=d.z; spT1[3]+=d.w;
        }
        // v = sp*|sp| / (se^2 + sp^2); vc += v   (se > 0 always)
#pragma unroll
        for (int c = 0; c < 4; ++c) {
            v0[c] = spT0[c] * fabsf(spT0[c]) *
                    RCPF(fmaf(seT0[c], seT0[c], spT0[c] * spT0[c]));
            v1[c] = spT1[c] * fabsf(spT1[c]) *
                    RCPF(fmaf(seT1[c], seT1[c], spT1[c] * spT1[c]));
            vc0[c] += v0[c];
            vc1[c] += v1[c];
        }
    }

    if (t < 4) {   // coq == t
        float4 o0, o1;
        o0.x = v0[0]; o0.y = v0[1]; o0.z = v0[2]; o0.w = v0[3];
        o1.x = v1[0]; o1.y = v1[1]; o1.z = v1[2]; o1.w = v1[3];
        *reinterpret_cast<float4*>(out + ((size_t)k * BDIM + b0)     * COUT + t * 4) = o0;
        *reinterpret_cast<float4*>(out + ((size_t)k * BDIM + b0 + 1) * COUT + t * 4) = o1;
    }
}

extern "C" void kernel_launch(void* const* d_in, const int* in_sizes, int n_in,
                              void* d_out, int out_size, void* d_ws, size_t ws_size,
                              hipStream_t stream) {
    const float* x = (const float*)d_in[0];
    const float* w = (const float*)d_in[1];
    const int* niter = (const int*)d_in[2];
    float* out = (float*)d_out;

    const int grid = KDIM * (BDIM / BT);   // 1280 blocks, k outer
    // ws layout: predG [1280][4608] uint4 = 9,437,184 B; sT 1280*32 f32 = 163,840 B
    uint4* predG = (uint4*)d_ws;
    float* sTG   = (float*)((char*)d_ws + (size_t)grid * SLAB * sizeof(uint4));

    capsule_pred_kernel<<<grid, NTHREADS, 0, stream>>>(x, w, predG, sTG);
    capsule_route_kernel<<<grid, NTHREADS, 0, stream>>>(predG, sTG, niter, out);
}

// Round 15
// 84.987 us; speedup vs baseline: 1.0298x; 1.0298x over previous
//
#include <hip/hip_runtime.h>
#include <hip/hip_bf16.h>

// Problem constants (from reference setup_inputs)
#define BDIM 256     // batch
#define NDIM 1152    // route nodes
#define CIN 8
#define KDIM 10      // num capsule groups
#define COUT 16
#define NTHREADS 512
#define BT 2         // batches per block -> W[k] read once per 2 b's
#define NPT 9        // n values per thread = NDIM / 128
#define SLAB (NDIM * 4)          // uint4s per block slab in predG (4608)

// R15 = R13/R14 split with the ONE attribute that has ever produced a
// no-spill compile of this loop body: amdgpu_waves_per_eu(4,4).
// Evidence: R9 monolith, same fenced phase-1, (4,4) -> 52 VGPR, WRITE 160 KB.
// R13 (no attr) -> 36 VGPR + 83 MB spill; R14 (8,8) -> 32 VGPR + 88 MB spill.
// (4,4) sets a 128-VGPR compile budget; RUNTIME occupancy follows actual
// usage (52 VGPR, 1 KB LDS -> 8 waves/EU), so the split still gets the
// 2x occupancy over the LDS-capped monolith.
//   kernel 1: fenced phase-1, packs bf16 pred -> predG[blk][t+512j]
//             (coalesced dwordx4), psum reduce -> sT. LDS 1 KB.
//   kernel 2: reads sT, streams predG twice for the routing iters. LDS 4 KB.

#if defined(__has_builtin)
#  if __has_builtin(__builtin_amdgcn_exp2f)
#    define EXP2F(x) __builtin_amdgcn_exp2f(x)
#  endif
#  if __has_builtin(__builtin_amdgcn_rcpf)
#    define RCPF(x) __builtin_amdgcn_rcpf(x)
#  endif
#endif
#ifndef EXP2F
#  define EXP2F(x) exp2f(x)
#endif
#ifndef RCPF
#  define RCPF(x) (1.0f / (x))
#endif
#define LOG2E 1.4426950408889634f

__device__ __forceinline__ unsigned pack2(float a, float b) {   // v_cvt_pk_bf16_f32
    union { __hip_bfloat162 h; unsigned u; } cv;
    cv.h = __float22bfloat162_rn(make_float2(a, b));
    return cv.u;
}
__device__ __forceinline__ float bf_lo(unsigned u) { return __uint_as_float(u << 16); }
__device__ __forceinline__ float bf_hi(unsigned u) { return __uint_as_float(u & 0xffff0000u); }

// 8 FMAs: one W float4 (one i) against both batches' x scalar
#define FMA8(i, w4)                                                      \
    a0[0] = fmaf(xs0[i], (w4).x, a0[0]);                                 \
    a0[1] = fmaf(xs0[i], (w4).y, a0[1]);                                 \
    a0[2] = fmaf(xs0[i], (w4).z, a0[2]);                                 \
    a0[3] = fmaf(xs0[i], (w4).w, a0[3]);                                 \
    a1[0] = fmaf(xs1[i], (w4).x, a1[0]);                                 \
    a1[1] = fmaf(xs1[i], (w4).y, a1[1]);                                 \
    a1[2] = fmaf(xs1[i], (w4).z, a1[2]);                                 \
    a1[3] = fmaf(xs1[i], (w4).w, a1[3]);

// ---------------- Kernel 1: pred production + per-block co sums ----------
__global__ __attribute__((amdgpu_flat_work_group_size(NTHREADS, NTHREADS),
                          amdgpu_waves_per_eu(4, 4)))
void capsule_pred_kernel(const float* __restrict__ x,      // [B, N, CIN]
                         const float* __restrict__ w,      // [K, N, CIN, COUT]
                         uint4*       __restrict__ predG,  // [1280][4608]
                         float*       __restrict__ sTG)    // [1280][32]
{
    __shared__ float4 redP[8][4][2];       // [wv][coq][bb] psum, 1 KB

    const int blk = blockIdx.x;
    const int k   = blk >> 7;              // / (BDIM/BT) == 128
    const int b0  = (blk & 127) * BT;
    const int t   = threadIdx.x;
    const int wv  = t >> 6;
    const int l   = t & 63;
    const int coq = t & 3;                 // co = coq*4 .. coq*4+3
    const int nb  = t >> 2;                // base n (0..127)

    const float* __restrict__ xb0 = x + (size_t)b0 * NDIM * CIN;
    const float* __restrict__ xb1 = xb0 + NDIM * CIN;
    const float* __restrict__ wk  = w + (size_t)k * NDIM * CIN * COUT + coq * 4;
    uint4* __restrict__ slab = predG + (size_t)blk * SLAB;

    float ps0[4] = {0.f,0.f,0.f,0.f}, ps1[4] = {0.f,0.f,0.f,0.f};

#pragma unroll 1
    for (int j = 0; j < NPT; ++j) {
        const int n = nb + 128 * j;
        const float4 xa0 = *reinterpret_cast<const float4*>(xb0 + n * CIN);
        const float4 xc0 = *reinterpret_cast<const float4*>(xb0 + n * CIN + 4);
        const float4 xa1 = *reinterpret_cast<const float4*>(xb1 + n * CIN);
        const float4 xc1 = *reinterpret_cast<const float4*>(xb1 + n * CIN + 4);
        const float xs0[8] = {xa0.x,xa0.y,xa0.z,xa0.w,xc0.x,xc0.y,xc0.z,xc0.w};
        const float xs1[8] = {xa1.x,xa1.y,xa1.z,xa1.w,xc1.x,xc1.y,xc1.z,xc1.w};
        const float* wr = wk + (size_t)n * (CIN * COUT);
        float a0[4] = {0.f,0.f,0.f,0.f}, a1[4] = {0.f,0.f,0.f,0.f};
        {   // i = 0,1
            const float4 wA = *reinterpret_cast<const float4*>(wr);
            const float4 wB = *reinterpret_cast<const float4*>(wr + COUT);
            FMA8(0, wA); FMA8(1, wB);
        }
        __builtin_amdgcn_sched_barrier(0);  // bound W loads in flight to 2
        {   // i = 2,3
            const float4 wA = *reinterpret_cast<const float4*>(wr + 2 * COUT);
            const float4 wB = *reinterpret_cast<const float4*>(wr + 3 * COUT);
            FMA8(2, wA); FMA8(3, wB);
        }
        __builtin_amdgcn_sched_barrier(0);
        {   // i = 4,5
            const float4 wA = *reinterpret_cast<const float4*>(wr + 4 * COUT);
            const float4 wB = *reinterpret_cast<const float4*>(wr + 5 * COUT);
            FMA8(4, wA); FMA8(5, wB);
        }
        __builtin_amdgcn_sched_barrier(0);
        {   // i = 6,7
            const float4 wA = *reinterpret_cast<const float4*>(wr + 6 * COUT);
            const float4 wB = *reinterpret_cast<const float4*>(wr + 7 * COUT);
            FMA8(6, wA); FMA8(7, wB);
        }
        uint4 qq;
        qq.x = pack2(a0[0], a0[1]);
        qq.y = pack2(a0[2], a0[3]);
        qq.z = pack2(a1[0], a1[1]);
        qq.w = pack2(a1[2], a1[3]);
        slab[t + 512 * j] = qq;             // coalesced global_store_dwordx4
#pragma unroll
        for (int c = 0; c < 4; ++c) { ps0[c] += a0[c]; ps1[c] += a1[c]; }
        __builtin_amdgcn_sched_barrier(0);  // stop cross-j load hoisting
    }

    // intra-wave reduce over the 16 lanes sharing coq
#pragma unroll
    for (int m = 4; m < 64; m <<= 1) {
#pragma unroll
        for (int c = 0; c < 4; ++c) {
            ps0[c] += __shfl_xor(ps0[c], m, 64);
            ps1[c] += __shfl_xor(ps1[c], m, 64);
        }
    }
    if (l < 4) {
        redP[wv][l][0] = make_float4(ps0[0], ps0[1], ps0[2], ps0[3]);
        redP[wv][l][1] = make_float4(ps1[0], ps1[1], ps1[2], ps1[3]);
    }
    __syncthreads();
    if (t < 8) {                            // t = coq*2 + bb
        const int cq = t >> 1, bb = t & 1;
        float4 s = make_float4(0.f, 0.f, 0.f, 0.f);
#pragma unroll 1
        for (int wvi = 0; wvi < 8; ++wvi) {
            const float4 r = redP[wvi][cq][bb];
            s.x += r.x; s.y += r.y; s.z += r.z; s.w += r.w;
        }
        *reinterpret_cast<float4*>(sTG + blk * 32 + t * 4) = s;
    }
}

// ---------------- Kernel 2: routing iterations over predG ----------------
__global__ __attribute__((amdgpu_flat_work_group_size(NTHREADS, NTHREADS),
                          amdgpu_waves_per_eu(4, 4)))
void capsule_route_kernel(const uint4* __restrict__ predG,  // [1280][4608]
                          const float* __restrict__ sTG,    // [1280][32]
                          const int*   __restrict__ niter_p,
                          float*       __restrict__ out)    // [K, B, COUT]
{
    __shared__ float4 redI[2][8][4][4];    // [buf][wv][coq][{se0,sp0,se1,sp1}], 4 KB

    const int blk = blockIdx.x;
    const int k   = blk >> 7;
    const int b0  = (blk & 127) * BT;
    const int t   = threadIdx.x;
    const int wv  = t >> 6;
    const int l   = t & 63;
    const int coq = t & 3;
    const uint4* __restrict__ slab = predG + (size_t)blk * SLAB;

    // per-coq sums from kernel 1 (4-lane broadcast loads)
    const float4 s0 = *reinterpret_cast<const float4*>(sTG + blk * 32 + coq * 8);
    const float4 s1 = *reinterpret_cast<const float4*>(sTG + blk * 32 + coq * 8 + 4);
    const float sT0[4] = {s0.x, s0.y, s0.z, s0.w};
    const float sT1[4] = {s1.x, s1.y, s1.z, s1.w};

    const int niter = *niter_p;

    // Iteration 1: logits == 0 -> uniform softmax -> s = mean_n(pred)
    // v = s|s|/(1+s^2), s = sT/N == sT*|sT| / (N^2 + sT^2)
    float v0[4], v1[4], vc0[4], vc1[4];
    {
        const float N2 = (float)NDIM * (float)NDIM;
#pragma unroll
        for (int c = 0; c < 4; ++c) {
            v0[c] = sT0[c] * fabsf(sT0[c]) * RCPF(fmaf(sT0[c], sT0[c], N2));
            v1[c] = sT1[c] * fabsf(sT1[c]) * RCPF(fmaf(sT1[c], sT1[c], N2));
            vc0[c] = v0[c];
            vc1[c] = v1[c];
        }
    }

    for (int it = 1; it < niter; ++it) {
        const int itb = it & 1;
        float vl0[4], vl1[4];
#pragma unroll
        for (int c = 0; c < 4; ++c) { vl0[c] = vc0[c] * LOG2E; vl1[c] = vc1[c] * LOG2E; }

        float se0[4]={0.f,0.f,0.f,0.f}, sp0[4]={0.f,0.f,0.f,0.f};
        float se1[4]={0.f,0.f,0.f,0.f}, sp1[4]={0.f,0.f,0.f,0.f};
#pragma unroll 3
        for (int j = 0; j < NPT; ++j) {
            const uint4 q = slab[t + 512 * j];   // coalesced dwordx4, L2/L3-hot
            const float p0[4] = {bf_lo(q.x), bf_hi(q.x), bf_lo(q.y), bf_hi(q.y)};
            const float p1[4] = {bf_lo(q.z), bf_hi(q.z), bf_lo(q.w), bf_hi(q.w)};
#pragma unroll
            for (int c = 0; c < 4; ++c) {
                const float e0 = EXP2F(p0[c] * vl0[c]);   // no max-sub needed
                se0[c] += e0;
                sp0[c] = fmaf(e0, p0[c], sp0[c]);
                const float e1 = EXP2F(p1[c] * vl1[c]);
                se1[c] += e1;
                sp1[c] = fmaf(e1, p1[c], sp1[c]);
            }
        }
#pragma unroll
        for (int m = 4; m < 64; m <<= 1) {
#pragma unroll
            for (int c = 0; c < 4; ++c) {
                se0[c] += __shfl_xor(se0[c], m, 64);
                sp0[c] += __shfl_xor(sp0[c], m, 64);
                se1[c] += __shfl_xor(se1[c], m, 64);
                sp1[c] += __shfl_xor(sp1[c], m, 64);
            }
        }
        if (l < 4) {
            redI[itb][wv][l][0] = make_float4(se0[0], se0[1], se0[2], se0[3]);
            redI[itb][wv][l][1] = make_float4(sp0[0], sp0[1], sp0[2], sp0[3]);
            redI[itb][wv][l][2] = make_float4(se1[0], se1[1], se1[2], se1[3]);
            redI[itb][wv][l][3] = make_float4(sp1[0], sp1[1], sp1[2], sp1[3]);
        }
        __syncthreads();   // double-buffered redI: one barrier per iteration
        float seT0[4]={0.f,0.f,0.f,0.f}, spT0[4]={0.f,0.f,0.f,0.f};
        float seT1[4]={0.f,0.f,0.f,0.f}, spT1[4]={0.f,0.f,0.f,0.f};
#pragma unroll 1
        for (int wvi = 0; wvi < 8; ++wvi) {   // unroll 1: <=4 float4 live
            const float4 a = redI[itb][wvi][coq][0];
            const float4 b = redI[itb][wvi][coq][1];
            const float4 c4 = redI[itb][wvi][coq][2];
            const float4 d = redI[itb][wvi][coq][3];
            seT0[0]+=a.x; seT0[1]+=a.y; seT0[2]+=a.z; seT0[3]+=a.w;
            spT0[0]+=b.x; spT0[1]+=b.y; spT0[2]+=b.z; spT0[3]+=b.w;
            seT1[0]+=c4.x; seT1[1]+=c4.y; seT1[2]+=c4.z; seT1[3]+=c4.w;
            spT1[0]+=d.x; spT1[1]+=d.y; spT1[2]+=d.z; spT1[3]+=d.w;
        }
        // v = sp*|sp| / (se^2 + sp^2); vc += v   (se > 0 always)
#pragma unroll
        for (int c = 0; c < 4; ++c) {
            v0[c] = spT0[c] * fabsf(spT0[c]) *
                    RCPF(fmaf(seT0[c], seT0[c], spT0[c] * spT0[c]));
            v1[c] = spT1[c] * fabsf(spT1[c]) *
                    RCPF(fmaf(seT1[c], seT1[c], spT1[c] * spT1[c]));
            vc0[c] += v0[c];
            vc1[c] += v1[c];
        }
    }

    if (t < 4) {   // coq == t
        float4 o0, o1;
        o0.x = v0[0]; o0.y = v0[1]; o0.z = v0[2]; o0.w = v0[3];
        o1.x = v1[0]; o1.y = v1[1]; o1.z = v1[2]; o1.w = v1[3];
        *reinterpret_cast<float4*>(out + ((size_t)k * BDIM + b0)     * COUT + t * 4) = o0;
        *reinterpret_cast<float4*>(out + ((size_t)k * BDIM + b0 + 1) * COUT + t * 4) = o1;
    }
}

extern "C" void kernel_launch(void* const* d_in, const int* in_sizes, int n_in,
                              void* d_out, int out_size, void* d_ws, size_t ws_size,
                              hipStream_t stream) {
    const float* x = (const float*)d_in[0];
    const float* w = (const float*)d_in[1];
    const int* niter = (const int*)d_in[2];
    float* out = (float*)d_out;

    const int grid = KDIM * (BDIM / BT);   // 1280 blocks, k outer
    // ws layout: predG [1280][4608] uint4 = 9,437,184 B; sT 1280*32 f32 = 163,840 B
    uint4* predG = (uint4*)d_ws;
    float* sTG   = (float*)((char*)d_ws + (size_t)grid * SLAB * sizeof(uint4));

    capsule_pred_kernel<<<grid, NTHREADS, 0, stream>>>(x, w, predG, sTG);
    capsule_route_kernel<<<grid, NTHREADS, 0, stream>>>(predG, sTG, niter, out);
}